// Round 1
// baseline (8795.065 us; speedup 1.0000x reference)
//
#include <hip/hip_runtime.h>

typedef __attribute__((ext_vector_type(8))) short s8v;   // 8 x bf16 (4 VGPRs)
typedef __attribute__((ext_vector_type(4))) float f4v;   // MFMA accumulator
typedef __attribute__((ext_vector_type(4))) unsigned u4v;

#define BB 8
#define TT 500
#define UU 120
#define UP1 121
#define VV 128
#define HH 320
#define G4 1280

// ---------------- helpers ----------------
__device__ __forceinline__ unsigned short f2bf(float x) {
  unsigned u = __builtin_bit_cast(unsigned, x);
  unsigned r = (u + 0x7FFFu + ((u >> 16) & 1u)) >> 16;  // RNE
  return (unsigned short)r;
}
__device__ __forceinline__ float sigf(float x)   { return 1.f / (1.f + __expf(-x)); }
__device__ __forceinline__ float tanh_f(float x) { return 2.f / (1.f + __expf(-2.f * x)) - 1.f; }

// agent-scope (L3-coherent) relaxed atomics — proven slow path
__device__ __forceinline__ unsigned ald32(const unsigned* p) {
  return __hip_atomic_load((unsigned*)p, __ATOMIC_RELAXED, __HIP_MEMORY_SCOPE_AGENT);
}
__device__ __forceinline__ void ast32(unsigned* p, unsigned v) {
  __hip_atomic_store(p, v, __ATOMIC_RELAXED, __HIP_MEMORY_SCOPE_AGENT);
}

// same-XCD fast path: sc0 loads read the XCD-shared L2 (bypass L1).
// issue-only (no waitcnt) so latency can hide under MFMA; wait3 ties the regs.
__device__ __forceinline__ void ld3_issue(const unsigned* p, unsigned voff,
                                          unsigned& v0, unsigned& v1, unsigned& v2) {
  asm volatile("global_load_dword %0, %3, %4 sc0\n\t"
               "global_load_dword %1, %3, %4 offset:256 sc0\n\t"
               "global_load_dword %2, %3, %4 offset:512 sc0"
               : "=v"(v0), "=v"(v1), "=v"(v2)
               : "v"(voff), "s"(p)
               : "memory");
}
__device__ __forceinline__ void wait3(unsigned& v0, unsigned& v1, unsigned& v2) {
  asm volatile("s_waitcnt vmcnt(0)" : "+v"(v0), "+v"(v1), "+v"(v2));
}

// ---------------- prep: out init ----------------
__global__ void prep_zero(float* out) {
  if (blockIdx.x == 0 && threadIdx.x == 0) out[0] = 0.f;
}

// ---------------- prep: bf16 conversions + bias folds (unchanged) ----------------
__global__ void prep_w(
    const float* __restrict__ whh0, const float* __restrict__ wih1,
    const float* __restrict__ whh1, const float* __restrict__ whhd,
    const float* __restrict__ wih0, const float* __restrict__ xs,
    const float* __restrict__ ewo,  const float* __restrict__ dwo,
    const float* __restrict__ bih1, const float* __restrict__ bhh1,
    const float* __restrict__ bih0, const float* __restrict__ bhh0,
    ushort* __restrict__ wb, ushort* __restrict__ wih0b, ushort* __restrict__ xsb,
    ushort* __restrict__ wob, ushort* __restrict__ dwob,
    float* __restrict__ bias1p, float* __restrict__ b0s)
{
  int i = blockIdx.x * blockDim.x + threadIdx.x;
  if (i < 1638400) {                       // 4 recurrent-ish mats [1280][320]
    int m = i / 409600, e = i - m * 409600;
    const float* src = (m == 0) ? whh0 : (m == 1) ? wih1 : (m == 2) ? whh1 : whhd;
    wb[i] = f2bf(src[e]);
  } else if (i < 1761280) {                // Wih0 [1280][80] -> [1280][96] zero-padded
    int e = i - 1638400;
    int row = e / 96, k = e - row * 96;
    wih0b[e] = (k < 80) ? f2bf(wih0[row * 80 + k]) : (ushort)0;
  } else if (i < 2145280) {                // xs [4000][80] -> [4000][96] zero-padded
    int e = i - 1761280;
    int row = e / 96, k = e - row * 96;
    xsb[e] = (k < 80) ? f2bf(xs[row * 80 + k]) : (ushort)0;
  } else if (i < 2186240) {                // enc_Wo [128][320]
    int e = i - 2145280;
    wob[e] = f2bf(ewo[e]);
  } else if (i < 2227200) {                // dec_Wo [128][320]
    int e = i - 2186240;
    dwob[e] = f2bf(dwo[e]);
  } else if (i < 2228480) {                // bias1 permuted [unit][gate]
    int e = i - 2227200;
    int uq = e >> 2, gq = e & 3;
    bias1p[e] = bih1[gq * HH + uq] + bhh1[gq * HH + uq];
  } else if (i < 2229760) {                // bih0+bhh0 summed (gate-row order)
    int e = i - 2228480;
    b0s[e] = bih0[e] + bhh0[e];
  }
}

// ---------------- xproj0: [4000,96]bf16 @ [96,1280] -> xp0[b][t][u][g] f32 (unchanged) ----------------
__global__ __launch_bounds__(256) void xproj0_mfma(
    const ushort* __restrict__ xsb, const ushort* __restrict__ wih0b,
    const float* __restrict__ b0s, float* __restrict__ xp0)
{
  const int mt = blockIdx.x;
  const int wave = threadIdx.x >> 6, lane = threadIdx.x & 63;
  const int q = lane >> 4, n16 = lane & 15;
  s8v a[3];
#pragma unroll
  for (int kt = 0; kt < 3; kt++)
    a[kt] = *(const s8v*)(xsb + (mt * 16 + n16) * 96 + kt * 32 + q * 8);
  for (int nt = wave; nt < 80; nt += 4) {
    s8v bf[3];
#pragma unroll
    for (int kt = 0; kt < 3; kt++)
      bf[kt] = *(const s8v*)(wih0b + (nt * 16 + n16) * 96 + kt * 32 + q * 8);
    f4v acc = {0.f, 0.f, 0.f, 0.f};
#pragma unroll
    for (int kt = 0; kt < 3; kt++)
      acc = __builtin_amdgcn_mfma_f32_16x16x32_bf16(a[kt], bf[kt], acc, 0, 0, 0);
    const int gr = nt * 16 + n16;
    const int gg = gr / HH;
    const int uu = gr - gg * HH;
    const float bias = b0s[gr];
#pragma unroll
    for (int r = 0; r < 4; r++) {
      int bt = mt * 16 + 4 * q + r;
      xp0[(size_t)bt * G4 + uu * 4 + gg] = acc[r] + bias;
    }
  }
}

// ---------------- decoder input projection: one-hot gather (unchanged) ----------------
__global__ __launch_bounds__(256) void xprojd_g(
    const int* __restrict__ ys, const float* __restrict__ dWih,
    const float* __restrict__ dbih, const float* __restrict__ dbhh,
    float* __restrict__ xpd)
{
  const int blk = blockIdx.x;                // 968 = 8 * 121
  const int b = blk / UP1, u = blk - b * UP1;
  int colv = -1;
  if (u > 0) colv = ys[b * UU + (u - 1)] - 1;
  for (int i = threadIdx.x; i < G4; i += 256) {
    int uu = i >> 2, gg = i & 3;
    int row = gg * HH + uu;
    float v = dbih[row] + dbhh[row];
    if (colv >= 0) v += dWih[row * 127 + colv];
    xpd[((size_t)b * UP1 + u) * G4 + i] = v;
  }
}

// ======================================================================
// Fused recurrences, restructured:
//   slots 0,1: L0 pair (each holds 640 rows of Whh0; exchanges h-halves)
//   slots 2,3: L1 pair (Whh1 halves; consumes xp1 from relays)
//   slots 4,5: relay pair: xp1[s] = Wih1 @ h0[s+1] + b1 (one-way, pipelined)
//   slots 6,7: decoder pair (Whhd halves, 121 steps)
// 64 candidate WGs launched; the 8 slots are elected from WGs sharing one
// XCD (pigeonhole guarantees >=8 of 64 on some XCD), so pair exchange rides
// the XCD-shared L2 (plain store + sc0 load). Every store also goes to an
// agent-scope (sc1) buffer; fast polls demote stickily to sc1 on timeout,
// so correctness never depends on placement or sc0 semantics.
// K-loop is own-half-first so the partner poll hides under ~970cy of MFMA.
// ======================================================================

#define XPLD(XV, OFS) { XV[0]=ald32(xpp+(OFS)); XV[1]=ald32(xpp+(OFS)+1); \
                        XV[2]=ald32(xpp+(OFS)+2); XV[3]=ald32(xpp+(OFS)+3); }
#define XACC(J, XV) { acc[J][0] += __uint_as_float(XV[0] & ~1u); \
                      acc[J][1] += __uint_as_float(XV[1] & ~1u); \
                      acc[J][2] += __uint_as_float(XV[2] & ~1u); \
                      acc[J][3] += __uint_as_float(XV[3] & ~1u); }

template<bool HASXQ, bool HASXP>
__device__ __forceinline__ void rec_run(
    const ushort* __restrict__ A,
    const float* __restrict__ xq_all, int bstride,
    const float* __restrict__ xp,
    unsigned* __restrict__ hslow, unsigned* __restrict__ hfast,
    int steps, int X, bool rd1, int tid,
    ushort (&hb)[2][16][344])
{
  const int wave = tid >> 6, lane = tid & 63;
  const int q = lane >> 4, n16 = lane & 15;
  const int uloc = n16 >> 2, g = n16 & 3;
  const int bcol = n16 & 7;
  const int Ub = X * 160 + wave * 20;        // this wave's 20 units
  const int Poff = (1 - X) * 160;            // partner's unit range
  const int k0 = X * 5, k1 = 5 - X * 5;      // own-half / partner-half K tiles

  // weights: 5 tiles x K=320 held in registers (200 VGPR/wave)
  s8v a[5][10];
#pragma unroll
  for (int j = 0; j < 5; ++j) {
    const int arow = g * HH + Ub + j * 4 + uloc;
#pragma unroll
    for (int kt = 0; kt < 10; ++kt)
      a[j][kt] = *(const s8v*)(A + (size_t)arow * HH + kt * 32 + q * 8);
  }

  const float* xqb = nullptr;
  if constexpr (HASXQ) xqb = xq_all + (size_t)bcol * bstride;

  float c[5] = {0.f, 0.f, 0.f, 0.f, 0.f};

  for (int t = 0; t < steps; ++t) {
    const int pb = t & 1;
    const unsigned pbase = (unsigned)t * 2560u + (unsigned)(wave * 320 + Poff);

    // ---- early-issue partner poll (resolved after own-half MFMA) ----
    unsigned v0 = 0, v1 = 0, v2 = 0;
    if (t > 0) {
      if (!rd1) ld3_issue(hfast, (pbase + (unsigned)lane) * 4u, v0, v1, v2);
      else { const unsigned* p = hslow + pbase + lane;
             v0 = ald32(p); v1 = ald32(p + 64); v2 = ald32(p + 128); }
    }

    // ---- early-issue xp1 poll (stage 1) ----
    u4v x0, x1, x2, x3, x4;
    const unsigned* xpp = nullptr;
    if constexpr (HASXP) {
      xpp = (const unsigned*)xp
          + (size_t)((unsigned)t * 8u + (unsigned)bcol) * (unsigned)G4
          + (unsigned)((Ub + q) * 4);
      XPLD(x0, 0); XPLD(x1, 16); XPLD(x2, 32); XPLD(x3, 48); XPLD(x4, 64);
    }

    // ---- C-init ----
    f4v acc[5];
    if constexpr (HASXQ) {
#pragma unroll
      for (int j = 0; j < 5; ++j)
        acc[j] = *(const f4v*)(xqb + (size_t)t * G4 + (Ub + j * 4 + q) * 4);
    } else {
#pragma unroll
      for (int j = 0; j < 5; ++j) acc[j] = (f4v){0.f, 0.f, 0.f, 0.f};
    }

    // ---- L2 prefetch of next step's C-init slab (xp0/xpd is HBM-cold) ----
    float pfv = 0.f;
    if constexpr (HASXQ) {
      if (lane < 40 && t + 1 < steps)
        pfv = *(xq_all + (size_t)wave * bstride + (size_t)(t + 1) * G4
                + X * 640 + lane * 16);
    }

    // ---- phase 1: own-half K (h available in LDS from previous step) ----
#pragma unroll
    for (int kl = 0; kl < 5; ++kl) {
      const int kt = k0 + kl;
      s8v b = *(const s8v*)&hb[pb][n16][kt * 32 + q * 8];
#pragma unroll
      for (int j = 0; j < 5; ++j)
        acc[j] = __builtin_amdgcn_mfma_f32_16x16x32_bf16(a[j][kt], b, acc[j], 0, 0, 0);
    }

    // ---- phase 2: resolve partner poll, relay into LDS ----
    if (t > 0) {
      bool got = false;
      if (!rd1) {
        wait3(v0, v1, v2);
        for (int tries = 0;;) {
          unsigned okm = v0 & v1 & (lane < 32 ? v2 : 1u);
          if (__all((int)(okm & 1u))) { got = true; break; }
          if (++tries > (1 << 12)) break;
          __builtin_amdgcn_s_sleep(1);
          ld3_issue(hfast, (pbase + (unsigned)lane) * 4u, v0, v1, v2);
          wait3(v0, v1, v2);
        }
        if (!got) rd1 = true;        // sticky demote to agent-scope path
      }
      if (!got) {
        const unsigned* p = hslow + pbase + lane;
        for (int tries = 0;;) {
          unsigned okm = v0 & v1 & (lane < 32 ? v2 : 1u);
          if (__all((int)(okm & 1u)) || ++tries > (1 << 17)) break;
          __builtin_amdgcn_s_sleep(2);
          v0 = ald32(p); v1 = ald32(p + 64); v2 = ald32(p + 128);
        }
      }
      hb[pb][wave][Poff + lane]       = (ushort)(v0 >> 16);
      hb[pb][wave][Poff + 64 + lane]  = (ushort)(v1 >> 16);
      if (lane < 32) hb[pb][wave][Poff + 128 + lane] = (ushort)(v2 >> 16);
    }
    __syncthreads();

    // ---- phase 3: partner-half K ----
#pragma unroll
    for (int kl = 0; kl < 5; ++kl) {
      const int kt = k1 + kl;
      s8v b = *(const s8v*)&hb[pb][n16][kt * 32 + q * 8];
#pragma unroll
      for (int j = 0; j < 5; ++j)
        acc[j] = __builtin_amdgcn_mfma_f32_16x16x32_bf16(a[j][kt], b, acc[j], 0, 0, 0);
    }

    // ---- phase 4: xp1 resolve + add (stage 1) ----
    if constexpr (HASXP) {
      for (int tries = 0;;) {
        unsigned okm = x0[0] & x0[1] & x0[2] & x0[3]
                     & x1[0] & x1[1] & x1[2] & x1[3]
                     & x2[0] & x2[1] & x2[2] & x2[3]
                     & x3[0] & x3[1] & x3[2] & x3[3]
                     & x4[0] & x4[1] & x4[2] & x4[3];
        bool ok = (n16 >= 8) || ((okm & 1u) != 0u);
        if (__all((int)ok) || ++tries > (1 << 17)) break;
        __builtin_amdgcn_s_sleep(2);
        XPLD(x0, 0); XPLD(x1, 16); XPLD(x2, 32); XPLD(x3, 48); XPLD(x4, 64);
      }
      XACC(0, x0); XACC(1, x1); XACC(2, x2); XACC(3, x3); XACC(4, x4);
    }

    // ---- phase 5/6: lane-local LSTM cell + dual-store + own LDS ----
    const int nb = pb ^ 1;
#pragma unroll
    for (int j = 0; j < 5; ++j) {
      float ig = sigf(acc[j][0]), fg = sigf(acc[j][1]);
      float gv = tanh_f(acc[j][2]), og = sigf(acc[j][3]);
      c[j] = fg * c[j] + ig * gv;
      float hv = og * tanh_f(c[j]);
      if (n16 < 8) {
        const int u = Ub + j * 4 + q;
        const unsigned short hbf = f2bf(hv);
        hb[nb][n16][u] = hbf;                              // own half for next step
        const unsigned tv = (((unsigned)hbf) << 16) | 1u;
        const size_t gidx = (size_t)(t + 1) * 2560 + (size_t)(n16 * 320 + u);
        ast32(hslow + gidx, tv);                           // agent-scope copy (always)
        hfast[gidx] = tv;                                  // same-XCD L2 copy (always)
      }
    }
    if constexpr (HASXQ) asm volatile("" :: "v"(pfv));     // keep prefetch alive
    __syncthreads();
  }
}

__device__ __forceinline__ void relay_run(
    const ushort* __restrict__ A, const float* __restrict__ b1p,
    const unsigned* __restrict__ h0, float* __restrict__ xp1,
    int X, int tid, ushort (&hb)[2][16][344])
{
  const int wave = tid >> 6, lane = tid & 63;
  const int q = lane >> 4, n16 = lane & 15;
  const int uloc = n16 >> 2, g = n16 & 3;
  const int bcol = n16 & 7;
  const int Ub = X * 160 + wave * 20;

  s8v a[5][10];
#pragma unroll
  for (int j = 0; j < 5; ++j) {
    const int arow = g * HH + Ub + j * 4 + uloc;
#pragma unroll
    for (int kt = 0; kt < 10; ++kt)
      a[j][kt] = *(const s8v*)(A + (size_t)arow * HH + kt * 32 + q * 8);
  }

  // early-issue poll for s=0 (h0[1]); loads resolve at first use
  unsigned v0, v1, v2, v3, v4;
  {
    const unsigned* p = h0 + 2560 + wave * 320 + lane;
    v0 = ald32(p); v1 = ald32(p + 64); v2 = ald32(p + 128);
    v3 = ald32(p + 192); v4 = ald32(p + 256);
  }

  for (int s = 0; s < TT; ++s) {
    const int pb = s & 1;
    const unsigned* p = h0 + (size_t)(s + 1) * 2560 + wave * 320 + lane;
    for (int tries = 0;;) {
      if (__all((int)(v0 & v1 & v2 & v3 & v4 & 1u)) || ++tries > (1 << 17)) break;
      __builtin_amdgcn_s_sleep(2);
      v0 = ald32(p); v1 = ald32(p + 64); v2 = ald32(p + 128);
      v3 = ald32(p + 192); v4 = ald32(p + 256);
    }
    hb[pb][wave][lane]       = (ushort)(v0 >> 16);
    hb[pb][wave][64 + lane]  = (ushort)(v1 >> 16);
    hb[pb][wave][128 + lane] = (ushort)(v2 >> 16);
    hb[pb][wave][192 + lane] = (ushort)(v3 >> 16);
    hb[pb][wave][256 + lane] = (ushort)(v4 >> 16);
    __syncthreads();

    // issue next step's poll now; its latency hides under the MFMAs below
    if (s + 1 < TT) {
      const unsigned* pn = h0 + (size_t)(s + 2) * 2560 + wave * 320 + lane;
      v0 = ald32(pn); v1 = ald32(pn + 64); v2 = ald32(pn + 128);
      v3 = ald32(pn + 192); v4 = ald32(pn + 256);
    }

    f4v acc[5];
#pragma unroll
    for (int j = 0; j < 5; ++j)
      acc[j] = *(const f4v*)(b1p + (Ub + j * 4 + q) * 4);
#pragma unroll
    for (int kt = 0; kt < 10; ++kt) {
      s8v b = *(const s8v*)&hb[pb][n16][kt * 32 + q * 8];
#pragma unroll
      for (int j = 0; j < 5; ++j)
        acc[j] = __builtin_amdgcn_mfma_f32_16x16x32_bf16(a[j][kt], b, acc[j], 0, 0, 0);
    }
    if (n16 < 8) {
#pragma unroll
      for (int j = 0; j < 5; ++j) {
        unsigned* dp = (unsigned*)xp1
            + (size_t)((unsigned)s * 8u + (unsigned)bcol) * (unsigned)G4
            + (unsigned)((Ub + j * 4 + q) * 4);
        ast32(dp,     __float_as_uint(acc[j][0]) | 1u);   // LSB tag on f32
        ast32(dp + 1, __float_as_uint(acc[j][1]) | 1u);
        ast32(dp + 2, __float_as_uint(acc[j][2]) | 1u);
        ast32(dp + 3, __float_as_uint(acc[j][3]) | 1u);
      }
    }
  }
}

__global__ __launch_bounds__(512, 1) void lstm_fused(
    const ushort* __restrict__ wb, const float* __restrict__ b1p,
    const float* __restrict__ xp0, const float* __restrict__ xpd,
    unsigned* __restrict__ h0u, unsigned* __restrict__ h1u, unsigned* __restrict__ hdu,
    unsigned* __restrict__ h0f, unsigned* __restrict__ h1f, unsigned* __restrict__ hdf,
    float* __restrict__ xp1, unsigned* __restrict__ xtab)
{
  __shared__ __align__(16) ushort hb[2][16][344];
  __shared__ int sh_slot;
  __shared__ unsigned sh_sx[8];
  const int tid = threadIdx.x;
  const int wg = blockIdx.x;

  // --- publish this WG's XCD id (tagged) ---
  unsigned myxcc = (unsigned)__builtin_amdgcn_s_getreg((31u << 11) | 20u) & 7u; // HW_REG_XCC_ID
  if (tid == 0) ast32(xtab + wg, (myxcc << 1) | 1u);

  // --- wave 0 reads the full 64-entry table and elects 8 co-XCD slots ---
  if (tid < 64) {
    unsigned e;
    for (int tries = 0;;) {
      e = ald32(xtab + tid);
      if (__all((int)(e & 1u)) || ++tries > (1 << 15)) break;
      __builtin_amdgcn_s_sleep(8);
    }
    unsigned xcd = (e & 1u) ? ((e >> 1) & 0xFu) : 0xFu;   // sentinel on timeout
    int best = 0, bestc = -1;
    for (int x = 0; x < 8; ++x) {
      int cnt = __popcll(__ballot(xcd == (unsigned)x));
      if (cnt > bestc) { bestc = cnt; best = x; }
    }
    unsigned long long mask = __ballot(xcd == (unsigned)best);
    int slotwg[8]; int ns = 0;
    unsigned long long m = mask;
    while (ns < 8 && m) { int b = __builtin_ctzll(m); slotwg[ns++] = b; m &= m - 1; }
    unsigned long long pad = ~mask;
    while (ns < 8) { int b = __builtin_ctzll(pad); slotwg[ns++] = b; pad &= pad - 1; }
    int ms = -1;
#pragma unroll
    for (int s = 0; s < 8; ++s) if (slotwg[s] == wg) ms = s;
    unsigned sxl[8];
#pragma unroll
    for (int s = 0; s < 8; ++s) sxl[s] = __shfl(xcd, slotwg[s]);
    if (tid == 0) {
      sh_slot = ms;
#pragma unroll
      for (int s = 0; s < 8; ++s) sh_sx[s] = sxl[s];
    }
  }
  // --- LDS zero (rows 8..15 feed unused MFMA B-columns, stay zero forever) ---
  for (int i = tid; i < 2 * 16 * 344; i += 512) ((ushort*)hb)[i] = 0;
  __syncthreads();

  const int myslot = sh_slot;
  if (myslot < 0) return;                    // non-elected WGs exit
  unsigned sx[8];
#pragma unroll
  for (int s = 0; s < 8; ++s) sx[s] = sh_sx[s];
  const unsigned a0 = sx[myslot];

  if (myslot < 2) {                          // L0 pair
    const int X = myslot;
    const unsigned px = sx[1 - X];
    const bool rd1 = (a0 > 7u) || (px > 7u) || (a0 != px);
    rec_run<true, false>(wb, xp0, TT * G4, nullptr, h0u, h0f, TT, X, rd1, tid, hb);
  } else if (myslot < 4) {                   // L1 pair
    const int X = myslot - 2;
    const unsigned px = sx[5 - myslot];
    const bool rd1 = (a0 > 7u) || (px > 7u) || (a0 != px);
    rec_run<false, true>(wb + 819200, nullptr, 0, xp1, h1u, h1f, TT, X, rd1, tid, hb);
  } else if (myslot < 6) {                   // relays (one-way, agent-scope)
    relay_run(wb + 409600, b1p, h0u, xp1, myslot - 4, tid, hb);
  } else {                                   // decoder pair
    const int X = myslot - 6;
    const unsigned px = sx[13 - myslot];
    const bool rd1 = (a0 > 7u) || (px > 7u) || (a0 != px);
    rec_run<true, false>(wb + 1228800, xpd, UP1 * G4, nullptr, hdu, hdf, UP1, X, rd1, tid, hb);
  }
}

// ---------------- output projections (unchanged; reads tagged u32 h) ----------------
__global__ __launch_bounds__(256) void proj_mfma(
    const unsigned* __restrict__ hseq, const ushort* __restrict__ wo,
    const float* __restrict__ bo, float* __restrict__ out2)
{
  const int t = blockIdx.x;
  const int wave = threadIdx.x >> 6, lane = threadIdx.x & 63;
  const int q = lane >> 4, n16 = lane & 15;
  union F { unsigned u[4]; s8v v; };
  F a[10];
  const unsigned long long* hp =
      (const unsigned long long*)hseq + (size_t)(t + 1) * 1280 + n16 * 160 + q * 4;
#pragma unroll
  for (int kt = 0; kt < 10; kt++)
#pragma unroll
    for (int j = 0; j < 4; j++) {
      unsigned long long r = (n16 < BB) ? hp[kt * 16 + j] : 0ull;
      unsigned lo = (unsigned)r, hi = (unsigned)(r >> 32);
      a[kt].u[j] = (lo >> 16) | (hi & 0xFFFF0000u);
    }
  for (int j = 0; j < 2; j++) {
    int nt = wave * 2 + j;
    s8v bf[10];
#pragma unroll
    for (int kt = 0; kt < 10; kt++)
      bf[kt] = *(const s8v*)(wo + (nt * 16 + n16) * HH + kt * 32 + q * 8);
    f4v acc = {0.f, 0.f, 0.f, 0.f};
#pragma unroll
    for (int kt = 0; kt < 10; kt++)
      acc = __builtin_amdgcn_mfma_f32_16x16x32_bf16(a[kt].v, bf[kt], acc, 0, 0, 0);
    int v = nt * 16 + n16;
    float bias = bo[v];
    if (q < 2) {
#pragma unroll
      for (int r = 0; r < 4; r++) {
        int b = 4 * q + r;
        out2[((size_t)t * 16 + b) * VV + v] = acc[r] + bias;
      }
    }
  }
}

// ---------------- per-cell logsumexp over V (unchanged) ----------------
__global__ __launch_bounds__(256) void lse_kernel(
    const float* __restrict__ enc2, const float* __restrict__ dec2,
    const int* __restrict__ ys, float* __restrict__ lb, float* __restrict__ ly)
{
  const int blk = blockIdx.x;                // 4000 = 8*500
  const int b = blk / TT, t = blk - b * TT;
  const int wave = threadIdx.x >> 6, lane = threadIdx.x & 63;
  const float* er = enc2 + ((size_t)t * 16 + b) * VV;
  const float e0 = er[lane], e1 = er[lane + 64];
  for (int u = wave; u < UP1; u += 4) {
    const float* dr = dec2 + ((size_t)u * 16 + b) * VV;
    float s0 = e0 + dr[lane], s1 = e1 + dr[lane + 64];
    float mx = fmaxf(s0, s1);
#pragma unroll
    for (int off = 32; off >= 1; off >>= 1) mx = fmaxf(mx, __shfl_xor(mx, off));
    float p = __expf(s0 - mx) + __expf(s1 - mx);
#pragma unroll
    for (int off = 32; off >= 1; off >>= 1) p += __shfl_xor(p, off);
    float lsev = mx + __logf(p);
    if (u < UU) {
      int y = ys[b * UU + u];
      float sy = (y < 64) ? __shfl(s0, y) : __shfl(s1, y - 64);
      if (lane == 0) ly[((size_t)b * TT + t) * UU + u] = sy - lsev;
    }
    if (lane == 0) lb[((size_t)b * TT + t) * UP1 + u] = s0 - lsev;
  }
}

// ---------------- anti-diagonal forward DP (unchanged) ----------------
__global__ __launch_bounds__(128) void dp_kernel(
    const float* __restrict__ lb, const float* __restrict__ ly,
    const int* __restrict__ xlen, const int* __restrict__ ylen,
    float* __restrict__ out)
{
  const int b = blockIdx.x;
  const int u = threadIdx.x;
  __shared__ float buf[2][UP1];
  const int tl = xlen[b], ul = ylen[b];
  if (u == 0) buf[0][0] = 0.f;
  __syncthreads();
  const float NEG = -1e30f;
  float nlb = 0.f, nly = 0.f;
  {
    int tn = 1 - u;
    if (u <= UU && tn >= 1 && tn < TT) nlb = lb[((size_t)b * TT + tn - 1) * UP1 + u];
    if (u >= 1 && u <= UU && tn >= 0 && tn < TT) nly = ly[((size_t)b * TT + tn) * UU + (u - 1)];
  }
  for (int d = 1; d <= TT - 1 + UU; d++) {
    float lbv = nlb, lyv = nly;
    {
      int tn = (d + 1) - u;
      nlb = 0.f; nly = 0.f;
      if (u <= UU && tn >= 1 && tn < TT) nlb = lb[((size_t)b * TT + tn - 1) * UP1 + u];
      if (u >= 1 && u <= UU && tn >= 0 && tn < TT) nly = ly[((size_t)b * TT + tn) * UU + (u - 1)];
    }
    const int t = d - u;
    float* cur = buf[d & 1];
    const float* prev = buf[(d & 1) ^ 1];
    if (u <= UU && t >= 0 && t < TT) {
      float a1 = (t >= 1) ? prev[u] + lbv : NEG;
      float a2 = (u >= 1) ? prev[u - 1] + lyv : NEG;
      float m = fmaxf(a1, a2);
      float val = (m <= -1e29f) ? NEG : m + __logf(1.f + __expf(-fabsf(a1 - a2)));
      cur[u] = val;
      if (t == tl - 1 && u == ul) {
        float lbt = lb[((size_t)b * TT + t) * UP1 + u];
        atomicAdd(out, -0.125f * (val + lbt));
      }
    }
    __syncthreads();
  }
}

// ---------------- launch ----------------
extern "C" void kernel_launch(void* const* d_in, const int* in_sizes, int n_in,
                              void* d_out, int out_size, void* d_ws, size_t ws_size,
                              hipStream_t stream) {
  (void)in_sizes; (void)n_in; (void)out_size;
  const float* xs    = (const float*)d_in[0];
  const int*   ys    = (const int*)d_in[1];
  const int*   xlen  = (const int*)d_in[2];
  const int*   ylen  = (const int*)d_in[3];
  const float* eWih0 = (const float*)d_in[4];
  const float* eWhh0 = (const float*)d_in[5];
  const float* ebih0 = (const float*)d_in[6];
  const float* ebhh0 = (const float*)d_in[7];
  const float* eWih1 = (const float*)d_in[8];
  const float* eWhh1 = (const float*)d_in[9];
  const float* ebih1 = (const float*)d_in[10];
  const float* ebhh1 = (const float*)d_in[11];
  const float* eWo   = (const float*)d_in[12];
  const float* ebo   = (const float*)d_in[13];
  const float* dWih  = (const float*)d_in[15];
  const float* dWhh  = (const float*)d_in[16];
  const float* dbih  = (const float*)d_in[17];
  const float* dbhh  = (const float*)d_in[18];
  const float* dWo   = (const float*)d_in[19];
  const float* dbo   = (const float*)d_in[20];

  char* ws = (char*)d_ws;
  const size_t OFF_XP0   = 1024;
  const size_t OFF_XPD   = OFF_XP0   + 20480000;  // 8*500*1280 f32
  const size_t OFF_H0    = OFF_XPD   + 4956160;   // 501 * 8*320 u32 (tagged, sc1)
  const size_t OFF_H1    = OFF_H0    + 5130240;
  const size_t OFF_HD    = OFF_H1    + 5130240;   // 122 * 8*320 u32
  const size_t OFF_WB    = OFF_HD    + 1249280;
  const size_t OFF_WIH0B = OFF_WB    + 3276800;   // 4*1280*320 bf16
  const size_t OFF_XSB   = OFF_WIH0B + 245760;    // 1280*96 bf16
  const size_t OFF_WOB   = OFF_XSB   + 768000;    // 4000*96 bf16
  const size_t OFF_DWOB  = OFF_WOB   + 81920;
  const size_t OFF_B1P   = OFF_DWOB  + 81920;
  const size_t OFF_B0S   = OFF_B1P   + 5120;
  const size_t OFF_ENC2  = OFF_B0S   + 5120;
  const size_t OFF_DEC2  = OFF_ENC2  + 4096000;   // 500*16*128 f32
  const size_t OFF_LB    = OFF_DEC2  + 991232;    // 121*16*128 f32
  const size_t OFF_LY    = OFF_LB    + 1936000;   // 8*500*121 f32
  const size_t OFF_XP1   = OFF_LY    + 1920000;   // 500*8*1280 f32 (tagged)
  const size_t OFF_H0F   = OFF_XP1   + 20480000;  // fast (same-XCD L2) h copies
  const size_t OFF_H1F   = OFF_H0F   + 5130240;
  const size_t OFF_HDF   = OFF_H1F   + 5130240;
  const size_t OFF_XCC   = OFF_HDF   + 1249280;   // 64 u32 XCD-id table
  const size_t TOTAL     = OFF_XCC   + 256;
  if (ws_size < TOTAL) return;

  float*    xp0   = (float*)(ws + OFF_XP0);
  float*    xpd   = (float*)(ws + OFF_XPD);
  unsigned* h0    = (unsigned*)(ws + OFF_H0);
  unsigned* h1    = (unsigned*)(ws + OFF_H1);
  unsigned* hd    = (unsigned*)(ws + OFF_HD);
  ushort*   wb    = (ushort*)(ws + OFF_WB);
  ushort*   wih0b = (ushort*)(ws + OFF_WIH0B);
  ushort*   xsb   = (ushort*)(ws + OFF_XSB);
  ushort*   wob   = (ushort*)(ws + OFF_WOB);
  ushort*   dwob  = (ushort*)(ws + OFF_DWOB);
  float*    b1p   = (float*)(ws + OFF_B1P);
  float*    b0s   = (float*)(ws + OFF_B0S);
  float*    enc2  = (float*)(ws + OFF_ENC2);
  float*    dec2  = (float*)(ws + OFF_DEC2);
  float*    lb    = (float*)(ws + OFF_LB);
  float*    ly    = (float*)(ws + OFF_LY);
  float*    xp1   = (float*)(ws + OFF_XP1);
  unsigned* h0f   = (unsigned*)(ws + OFF_H0F);
  unsigned* h1f   = (unsigned*)(ws + OFF_H1F);
  unsigned* hdf   = (unsigned*)(ws + OFF_HDF);
  unsigned* xtab  = (unsigned*)(ws + OFF_XCC);
  float*    out   = (float*)d_out;

  hipLaunchKernelGGL(prep_zero, dim3(1), dim3(64), 0, stream, out);
  hipLaunchKernelGGL(prep_w, dim3(8710), dim3(256), 0, stream,
                     eWhh0, eWih1, eWhh1, dWhh, eWih0, xs, eWo, dWo,
                     ebih1, ebhh1, ebih0, ebhh0,
                     wb, wih0b, xsb, wob, dwob, b1p, b0s);
  hipLaunchKernelGGL(xproj0_mfma, dim3(250), dim3(256), 0, stream, xsb, wih0b, b0s, xp0);
  hipLaunchKernelGGL(xprojd_g, dim3(968), dim3(256), 0, stream, ys, dWih, dbih, dbhh, xpd);
  hipLaunchKernelGGL(lstm_fused, dim3(64), dim3(512), 0, stream,
                     wb, b1p, xp0, xpd, h0, h1, hd, h0f, h1f, hdf, xp1, xtab);
  hipLaunchKernelGGL(proj_mfma, dim3(500), dim3(256), 0, stream, h1, wob, ebo, enc2);
  hipLaunchKernelGGL(proj_mfma, dim3(121), dim3(256), 0, stream, hd, dwob, dbo, dec2);
  hipLaunchKernelGGL(lse_kernel, dim3(4000), dim3(256), 0, stream, enc2, dec2, ys, lb, ly);
  hipLaunchKernelGGL(dp_kernel, dim3(8), dim3(128), 0, stream, lb, ly, xlen, ylen, out);
}

// Round 2
// 4136.956 us; speedup vs baseline: 2.1260x; 2.1260x over previous
//
#include <hip/hip_runtime.h>

typedef __attribute__((ext_vector_type(8))) short s8v;   // 8 x bf16 (4 VGPRs)
typedef __attribute__((ext_vector_type(4))) float f4v;   // MFMA accumulator

#define BB 8
#define TT 500
#define UU 120
#define UP1 121
#define VV 128
#define HH 320
#define G4 1280

// ---------------- helpers ----------------
__device__ __forceinline__ unsigned short f2bf(float x) {
  unsigned u = __builtin_bit_cast(unsigned, x);
  unsigned r = (u + 0x7FFFu + ((u >> 16) & 1u)) >> 16;  // RNE
  return (unsigned short)r;
}
__device__ __forceinline__ float sigf(float x)   { return 1.f / (1.f + __expf(-x)); }
__device__ __forceinline__ float tanh_f(float x) { return 2.f / (1.f + __expf(-2.f * x)) - 1.f; }

// agent-scope (L3-coherent) relaxed atomics — proven slow path
__device__ __forceinline__ unsigned ald32(const unsigned* p) {
  return __hip_atomic_load((unsigned*)p, __ATOMIC_RELAXED, __HIP_MEMORY_SCOPE_AGENT);
}
__device__ __forceinline__ void ast32(unsigned* p, unsigned v) {
  __hip_atomic_store(p, v, __ATOMIC_RELAXED, __HIP_MEMORY_SCOPE_AGENT);
}

// same-XCD fast path: sc0 loads bypass L1 and read the XCD-shared L2.
__device__ __forceinline__ void ld5_issue(const unsigned* p, unsigned voff,
    unsigned& v0, unsigned& v1, unsigned& v2, unsigned& v3, unsigned& v4) {
  asm volatile("global_load_dword %0, %5, %6 sc0\n\t"
               "global_load_dword %1, %5, %6 offset:256 sc0\n\t"
               "global_load_dword %2, %5, %6 offset:512 sc0\n\t"
               "global_load_dword %3, %5, %6 offset:768 sc0\n\t"
               "global_load_dword %4, %5, %6 offset:1024 sc0\n\t"
               "s_waitcnt vmcnt(0)"
               : "=v"(v0), "=v"(v1), "=v"(v2), "=v"(v3), "=v"(v4)
               : "v"(voff), "s"(p)
               : "memory");
}

// poll one 320-unit batch-row slice (5 u32/lane). Fast (same-XCD L2) first,
// sticky demote to agent-scope on timeout — correctness never depends on
// placement or sc0 semantics.
__device__ __forceinline__ void poll5(
    const unsigned* __restrict__ fastp, const unsigned* __restrict__ slowp,
    unsigned base, int lane, bool& slow, unsigned (&v)[5])
{
  if (!slow) {
    int tries = 0;
    for (;;) {
      ld5_issue(fastp, (base + (unsigned)lane) * 4u, v[0], v[1], v[2], v[3], v[4]);
      unsigned a = v[0] & v[1] & v[2] & v[3] & v[4];
      if (__all((int)(a & 1u))) return;
      if (++tries > 4096) { slow = true; break; }
      __builtin_amdgcn_s_sleep(1);
    }
  }
  const unsigned* p = slowp + base + lane;
  int tries = 0;
  for (;;) {
#pragma unroll
    for (int j = 0; j < 5; ++j) v[j] = ald32(p + j * 64);
    unsigned a = v[0] & v[1] & v[2] & v[3] & v[4];
    if (__all((int)(a & 1u)) || ++tries > (1 << 17)) return;
    __builtin_amdgcn_s_sleep(2);
  }
}

// ---------------- prep: tagged zeros for the t=0 state (slow + fast copies) ----------------
__global__ void prep_zero(unsigned* h0, unsigned* h1, unsigned* hd,
                          unsigned* h0f, unsigned* h1f, unsigned* hdf, float* out) {
  int i = blockIdx.x * blockDim.x + threadIdx.x;
  if (i < 2560) {
    h0[i] = 1u; h1[i] = 1u; hd[i] = 1u;
    h0f[i] = 1u; h1f[i] = 1u; hdf[i] = 1u;
  }
  if (i == 0) out[0] = 0.f;
}

// ---------------- prep: bf16 conversions + bias folds ----------------
__global__ void prep_w(
    const float* __restrict__ whh0, const float* __restrict__ wih1,
    const float* __restrict__ whh1, const float* __restrict__ whhd,
    const float* __restrict__ wih0, const float* __restrict__ xs,
    const float* __restrict__ ewo,  const float* __restrict__ dwo,
    const float* __restrict__ bih1, const float* __restrict__ bhh1,
    const float* __restrict__ bih0, const float* __restrict__ bhh0,
    ushort* __restrict__ wb, ushort* __restrict__ wih0b, ushort* __restrict__ xsb,
    ushort* __restrict__ wob, ushort* __restrict__ dwob,
    float* __restrict__ bias1p, float* __restrict__ b0s)
{
  int i = blockIdx.x * blockDim.x + threadIdx.x;
  if (i < 1638400) {                       // 4 recurrent-ish mats [1280][320]
    int m = i / 409600, e = i - m * 409600;
    const float* src = (m == 0) ? whh0 : (m == 1) ? wih1 : (m == 2) ? whh1 : whhd;
    wb[i] = f2bf(src[e]);
  } else if (i < 1761280) {                // Wih0 [1280][80] -> [1280][96] zero-padded
    int e = i - 1638400;
    int row = e / 96, k = e - row * 96;
    wih0b[e] = (k < 80) ? f2bf(wih0[row * 80 + k]) : (ushort)0;
  } else if (i < 2145280) {                // xs [4000][80] -> [4000][96] zero-padded
    int e = i - 1761280;
    int row = e / 96, k = e - row * 96;
    xsb[e] = (k < 80) ? f2bf(xs[row * 80 + k]) : (ushort)0;
  } else if (i < 2186240) {                // enc_Wo [128][320]
    int e = i - 2145280;
    wob[e] = f2bf(ewo[e]);
  } else if (i < 2227200) {                // dec_Wo [128][320]
    int e = i - 2186240;
    dwob[e] = f2bf(dwo[e]);
  } else if (i < 2228480) {                // bias1 permuted [unit][gate]
    int e = i - 2227200;
    int uq = e >> 2, gq = e & 3;
    bias1p[e] = bih1[gq * HH + uq] + bhh1[gq * HH + uq];
  } else if (i < 2229760) {                // bih0+bhh0 summed (gate-row order)
    int e = i - 2228480;
    b0s[e] = bih0[e] + bhh0[e];
  }
}

// ---------------- xproj for layer0: [4000,96]bf16 @ [96,1280] -> xp0[b][t][u][g] f32 ----------------
__global__ __launch_bounds__(256) void xproj0_mfma(
    const ushort* __restrict__ xsb, const ushort* __restrict__ wih0b,
    const float* __restrict__ b0s, float* __restrict__ xp0)
{
  const int mt = blockIdx.x;                 // 250 tiles of 16 (b,t)-rows
  const int wave = threadIdx.x >> 6, lane = threadIdx.x & 63;
  const int q = lane >> 4, n16 = lane & 15;
  s8v a[3];
#pragma unroll
  for (int kt = 0; kt < 3; kt++)
    a[kt] = *(const s8v*)(xsb + (mt * 16 + n16) * 96 + kt * 32 + q * 8);
  for (int nt = wave; nt < 80; nt += 4) {
    s8v bf[3];
#pragma unroll
    for (int kt = 0; kt < 3; kt++)
      bf[kt] = *(const s8v*)(wih0b + (nt * 16 + n16) * 96 + kt * 32 + q * 8);
    f4v acc = {0.f, 0.f, 0.f, 0.f};
#pragma unroll
    for (int kt = 0; kt < 3; kt++)
      acc = __builtin_amdgcn_mfma_f32_16x16x32_bf16(a[kt], bf[kt], acc, 0, 0, 0);
    const int gr = nt * 16 + n16;            // D col = gate row
    const int gg = gr / HH;
    const int uu = gr - gg * HH;
    const float bias = b0s[gr];
#pragma unroll
    for (int r = 0; r < 4; r++) {
      int bt = mt * 16 + 4 * q + r;          // D row = (b,t) row
      xp0[(size_t)bt * G4 + uu * 4 + gg] = acc[r] + bias;
    }
  }
}

// ---------------- decoder input projection: one-hot gather ----------------
__global__ __launch_bounds__(256) void xprojd_g(
    const int* __restrict__ ys, const float* __restrict__ dWih,
    const float* __restrict__ dbih, const float* __restrict__ dbhh,
    float* __restrict__ xpd)
{
  const int blk = blockIdx.x;                // 968 = 8 * 121
  const int b = blk / UP1, u = blk - b * UP1;
  int colv = -1;
  if (u > 0) colv = ys[b * UU + (u - 1)] - 1;   // embed row id>=1 -> one-hot at id-1
  for (int i = threadIdx.x; i < G4; i += 256) {
    int uu = i >> 2, gg = i & 3;
    int row = gg * HH + uu;
    float v = dbih[row] + dbhh[row];
    if (colv >= 0) v += dWih[row * 127 + colv];
    xpd[((size_t)b * UP1 + u) * G4 + i] = v;
  }
}

// ---------------- fused recurrences: R0 structure + XCD-co-located transport ----------------
// 3 stages x 5 slots (512 thr = 8 waves each). 128 candidate WGs launched;
// wg0/wave0 is the SINGLE decider: it reads all 128 published XCC_IDs,
// picks the modal XCD (pigeonhole: >=16 of 128), assigns slots 0..14 to the
// first 15 WGs on it, and publishes assignments in a tagged table. All WGs
// poll their own entry -> consistent by construction. Elected WGs exchange h
// through plain stores + sc0 loads in the SHARED per-XCD L2; every store also
// goes to the agent-scope buffer, and polls demote stickily on timeout.
__global__ __launch_bounds__(512, 1) void lstm_fused(
    const ushort* __restrict__ wb, const float* __restrict__ b1p,
    const float* __restrict__ xp0, const float* __restrict__ xpd,
    unsigned* __restrict__ h0u, unsigned* __restrict__ h1u, unsigned* __restrict__ hdu,
    unsigned* __restrict__ h0f, unsigned* __restrict__ h1f, unsigned* __restrict__ hdf,
    unsigned* __restrict__ xtab, unsigned* __restrict__ xres)
{
  const int wg = blockIdx.x;
  const int tid = threadIdx.x;
  __shared__ ushort hbS[2][16][328];        // double-buffered h (recurrent input)
  __shared__ ushort hbI[2][16][328];        // stage 1 only: h0[t+1] input
  __shared__ int sh_slot, sh_fast;

  // --- publish this WG's XCD id (tagged) ---
  unsigned myxcc = (unsigned)__builtin_amdgcn_s_getreg((31u << 11) | 20u) & 7u; // HW_REG_XCC_ID
  if (tid == 0) ast32(xtab + wg, (myxcc << 1) | 1u);

  // --- single decider: wg0 wave0 assigns all 15 slots on the modal XCD ---
  if (wg == 0 && tid < 64) {
    unsigned e0, e1; int tries = 0;
    for (;;) {
      e0 = ald32(xtab + tid);
      e1 = ald32(xtab + 64 + tid);
      if (__all((int)(e0 & e1 & 1u)) || ++tries > (1 << 18)) break;
      __builtin_amdgcn_s_sleep(8);
    }
    unsigned x0 = (e0 & 1u) ? ((e0 >> 1) & 15u) : 15u;
    unsigned x1 = (e1 & 1u) ? ((e1 >> 1) & 15u) : 15u;
    int best = 0, bestc = -1;
    for (int x = 0; x < 8; ++x) {
      int c = __popcll(__ballot(x0 == (unsigned)x)) + __popcll(__ballot(x1 == (unsigned)x));
      if (c > bestc) { bestc = c; best = x; }
    }
    const unsigned long long mlo = __ballot(x0 == (unsigned)best);
    const unsigned long long mhi = __ballot(x1 == (unsigned)best);
    const unsigned long long pre = (1ull << tid) - 1ull;
    const int fast = (bestc >= 15) ? 1 : 0;
    int slot0, slot1;
    if (x0 == (unsigned)best) {
      int r = __popcll(mlo & pre);
      slot0 = (r < 15) ? r : -1;
    } else {
      int r = bestc + __popcll(~mlo & pre);
      slot0 = (!fast && r < 15) ? r : -1;
    }
    if (x1 == (unsigned)best) {
      int r = __popcll(mlo) + __popcll(mhi & pre);
      slot1 = (r < 15) ? r : -1;
    } else {
      int r = bestc + __popcll(~mlo) + __popcll(~mhi & pre);
      slot1 = (!fast && r < 15) ? r : -1;
    }
    ast32(xres + tid,      ((unsigned)(slot0 + 1) << 2) | ((unsigned)fast << 1) | 1u);
    ast32(xres + tid + 64, ((unsigned)(slot1 + 1) << 2) | ((unsigned)fast << 1) | 1u);
  }

  // --- every WG polls its own assignment (decider always writes all 128) ---
  if (tid == 0) {
    unsigned r; int tries = 0;
    for (;;) {
      r = ald32(xres + wg);
      if ((r & 1u) || ++tries > (1 << 20)) break;
      __builtin_amdgcn_s_sleep(8);
    }
    sh_slot = (r & 1u) ? ((int)(r >> 2) - 1) : -1;
    sh_fast = (int)((r >> 1) & 1u);
  }

  // zero rows 8..15 once (these feed the unused MFMA B-columns)
  for (int i = tid; i < 8 * 328; i += 512) {
    int rr = 8 + i / 328, ci = i % 328;
    hbS[0][rr][ci] = 0; hbS[1][rr][ci] = 0;
    hbI[0][rr][ci] = 0; hbI[1][rr][ci] = 0;
  }
  __syncthreads();

  const int slot = sh_slot;
  const bool fastok = (sh_fast != 0);
  if (slot < 0) return;                      // non-elected WGs exit

  const int stage = slot / 5;
  const int gw = slot - stage * 5;
  const int wave = tid >> 6, lane = tid & 63;
  const int q = lane >> 4, n16 = lane & 15;
  const int uloc = n16 >> 2, g = n16 & 3;
  const int w = gw * 8 + wave;              // wave-in-stage [0,40)
  const int ubase = w * 8;                  // this wave owns units [ubase, ubase+8)
  const int bcol = n16 & 7;
  const bool act = (n16 < BB);
  const bool two = (stage == 1);

  const ushort* A = wb + (stage == 0 ? 0 : (stage == 1 ? 819200 : 1228800));
  s8v afr[2][10], ainfr[2][10];
#pragma unroll
  for (int tile = 0; tile < 2; tile++) {
    const int arow = g * HH + ubase + tile * 4 + uloc;
#pragma unroll
    for (int kt = 0; kt < 10; kt++)
      afr[tile][kt] = *(const s8v*)(A + arow * HH + kt * 32 + q * 8);
  }
  if (two) {
    const ushort* Win = wb + 409600;        // Wih1
#pragma unroll
    for (int tile = 0; tile < 2; tile++) {
      const int arow = g * HH + ubase + tile * 4 + uloc;
#pragma unroll
      for (int kt = 0; kt < 10; kt++)
        ainfr[tile][kt] = *(const s8v*)(Win + arow * HH + kt * 32 + q * 8);
    }
  }

  const int steps = (stage == 2) ? UP1 : TT;
  unsigned* hio  = (stage == 0) ? h0u : ((stage == 1) ? h1u : hdu);
  unsigned* hiof = (stage == 0) ? h0f : ((stage == 1) ? h1f : hdf);

  f4v bias4[2];
  const float* xq = 0;
  if (stage == 0)      xq = xp0 + (size_t)bcol * TT * G4;
  else if (stage == 2) xq = xpd + (size_t)bcol * UP1 * G4;
  else {
#pragma unroll
    for (int tile = 0; tile < 2; tile++)
      bias4[tile] = *(const f4v*)(b1p + (ubase + tile * 4 + q) * 4);
  }

  float c0 = 0.f, c1 = 0.f;
  bool slowS = !fastok, slowI = !fastok;

  for (int t = 0; t < steps; t++) {
    const int pb = t & 1;

    // ---- wave w polls batch-row w of the needed h buffers, relays into LDS ----
    {
      unsigned v[5];
      poll5(hiof, hio, (unsigned)t * 2560u + (unsigned)(wave * 320), lane, slowS, v);
#pragma unroll
      for (int j = 0; j < 5; j++) hbS[pb][wave][j * 64 + lane] = (ushort)(v[j] >> 16);
    }
    if (two) {
      unsigned v[5];
      poll5(h0f, h0u, (unsigned)(t + 1) * 2560u + (unsigned)(wave * 320), lane, slowI, v);
#pragma unroll
      for (int j = 0; j < 5; j++) hbI[pb][wave][j * 64 + lane] = (ushort)(v[j] >> 16);
    }
    __syncthreads();

    // ---- C-init ----
    f4v acc[2];
    if (stage == 1) {
      acc[0] = bias4[0]; acc[1] = bias4[1];
    } else {
#pragma unroll
      for (int tile = 0; tile < 2; tile++)
        acc[tile] = *(const f4v*)(xq + (size_t)t * G4 + (ubase + tile * 4 + q) * 4);
    }

    // ---- B-frags straight from LDS + MFMAs ----
#pragma unroll
    for (int kt = 0; kt < 10; kt++) {
      s8v b = *(const s8v*)&hbS[pb][n16][kt * 32 + q * 8];
      acc[0] = __builtin_amdgcn_mfma_f32_16x16x32_bf16(afr[0][kt], b, acc[0], 0, 0, 0);
      acc[1] = __builtin_amdgcn_mfma_f32_16x16x32_bf16(afr[1][kt], b, acc[1], 0, 0, 0);
    }
    if (two) {
#pragma unroll
      for (int kt = 0; kt < 10; kt++) {
        s8v b = *(const s8v*)&hbI[pb][n16][kt * 32 + q * 8];
        acc[0] = __builtin_amdgcn_mfma_f32_16x16x32_bf16(ainfr[0][kt], b, acc[0], 0, 0, 0);
        acc[1] = __builtin_amdgcn_mfma_f32_16x16x32_bf16(ainfr[1][kt], b, acc[1], 0, 0, 0);
      }
    }

    // ---- lane-local LSTM cell: acc[tile] = (i,f,g,o) for unit ubase+tile*4+q, batch n16 ----
    float hv0, hv1;
    {
      float ig = sigf(acc[0][0]), fg = sigf(acc[0][1]);
      float gv = tanh_f(acc[0][2]), og = sigf(acc[0][3]);
      c0 = fg * c0 + ig * gv; hv0 = og * tanh_f(c0);
    }
    {
      float ig = sigf(acc[1][0]), fg = sigf(acc[1][1]);
      float gv = tanh_f(acc[1][2]), og = sigf(acc[1][3]);
      c1 = fg * c1 + ig * gv; hv1 = og * tanh_f(c1);
    }
    if (act) {
      const size_t rbase = (size_t)(t + 1) * 2560 + (size_t)(n16 * 320);
      const unsigned tv0 = (((unsigned)f2bf(hv0)) << 16) | 1u;
      const unsigned tv1 = (((unsigned)f2bf(hv1)) << 16) | 1u;
      ast32(hio + rbase + ubase + q,     tv0);   // agent-scope copy (always)
      ast32(hio + rbase + ubase + 4 + q, tv1);
      hiof[rbase + ubase + q]     = tv0;         // same-XCD L2 copy (always)
      hiof[rbase + ubase + 4 + q] = tv1;
    }
  }
}

// ---------------- output projections: h(tagged u32)[16,320] @ Wo^T -> out2[t][16][128] ----------------
__global__ __launch_bounds__(256) void proj_mfma(
    const unsigned* __restrict__ hseq, const ushort* __restrict__ wo,
    const float* __restrict__ bo, float* __restrict__ out2)
{
  const int t = blockIdx.x;
  const int wave = threadIdx.x >> 6, lane = threadIdx.x & 63;
  const int q = lane >> 4, n16 = lane & 15;
  union F { unsigned u[4]; s8v v; };
  F a[10];
  const unsigned long long* hp =
      (const unsigned long long*)hseq + (size_t)(t + 1) * 1280 + n16 * 160 + q * 4;
#pragma unroll
  for (int kt = 0; kt < 10; kt++)
#pragma unroll
    for (int j = 0; j < 4; j++) {
      unsigned long long r = (n16 < BB) ? hp[kt * 16 + j] : 0ull;
      unsigned lo = (unsigned)r, hi = (unsigned)(r >> 32);
      a[kt].u[j] = (lo >> 16) | (hi & 0xFFFF0000u);
    }
  for (int j = 0; j < 2; j++) {
    int nt = wave * 2 + j;
    s8v bf[10];
#pragma unroll
    for (int kt = 0; kt < 10; kt++)
      bf[kt] = *(const s8v*)(wo + (nt * 16 + n16) * HH + kt * 32 + q * 8);
    f4v acc = {0.f, 0.f, 0.f, 0.f};
#pragma unroll
    for (int kt = 0; kt < 10; kt++)
      acc = __builtin_amdgcn_mfma_f32_16x16x32_bf16(a[kt].v, bf[kt], acc, 0, 0, 0);
    int v = nt * 16 + n16;
    float bias = bo[v];
    if (q < 2) {
#pragma unroll
      for (int r = 0; r < 4; r++) {
        int b = 4 * q + r;                   // D row = batch
        out2[((size_t)t * 16 + b) * VV + v] = acc[r] + bias;
      }
    }
  }
}

// ---------------- per-cell logsumexp over V: produce lb[b][t][u], ly[b][t][u] ----------------
__global__ __launch_bounds__(256) void lse_kernel(
    const float* __restrict__ enc2, const float* __restrict__ dec2,
    const int* __restrict__ ys, float* __restrict__ lb, float* __restrict__ ly)
{
  const int blk = blockIdx.x;                // 4000 = 8*500
  const int b = blk / TT, t = blk - b * TT;
  const int wave = threadIdx.x >> 6, lane = threadIdx.x & 63;
  const float* er = enc2 + ((size_t)t * 16 + b) * VV;
  const float e0 = er[lane], e1 = er[lane + 64];
  for (int u = wave; u < UP1; u += 4) {
    const float* dr = dec2 + ((size_t)u * 16 + b) * VV;
    float s0 = e0 + dr[lane], s1 = e1 + dr[lane + 64];
    float mx = fmaxf(s0, s1);
#pragma unroll
    for (int off = 32; off >= 1; off >>= 1) mx = fmaxf(mx, __shfl_xor(mx, off));
    float p = __expf(s0 - mx) + __expf(s1 - mx);
#pragma unroll
    for (int off = 32; off >= 1; off >>= 1) p += __shfl_xor(p, off);
    float lsev = mx + __logf(p);
    if (u < UU) {
      int y = ys[b * UU + u];                // in [1,127]
      float sy = (y < 64) ? __shfl(s0, y) : __shfl(s1, y - 64);
      if (lane == 0) ly[((size_t)b * TT + t) * UU + u] = sy - lsev;
    }
    if (lane == 0) lb[((size_t)b * TT + t) * UP1 + u] = s0 - lsev;  // lane0: v=0
  }
}

// ---------------- anti-diagonal forward DP, one block per sample ----------------
__global__ __launch_bounds__(128) void dp_kernel(
    const float* __restrict__ lb, const float* __restrict__ ly,
    const int* __restrict__ xlen, const int* __restrict__ ylen,
    float* __restrict__ out)
{
  const int b = blockIdx.x;
  const int u = threadIdx.x;
  __shared__ float buf[2][UP1];
  const int tl = xlen[b], ul = ylen[b];
  if (u == 0) buf[0][0] = 0.f;
  __syncthreads();
  const float NEG = -1e30f;
  float nlb = 0.f, nly = 0.f;
  {
    int tn = 1 - u;
    if (u <= UU && tn >= 1 && tn < TT) nlb = lb[((size_t)b * TT + tn - 1) * UP1 + u];
    if (u >= 1 && u <= UU && tn >= 0 && tn < TT) nly = ly[((size_t)b * TT + tn) * UU + (u - 1)];
  }
  for (int d = 1; d <= TT - 1 + UU; d++) {   // up to 619
    float lbv = nlb, lyv = nly;
    {
      int tn = (d + 1) - u;
      nlb = 0.f; nly = 0.f;
      if (u <= UU && tn >= 1 && tn < TT) nlb = lb[((size_t)b * TT + tn - 1) * UP1 + u];
      if (u >= 1 && u <= UU && tn >= 0 && tn < TT) nly = ly[((size_t)b * TT + tn) * UU + (u - 1)];
    }
    const int t = d - u;
    float* cur = buf[d & 1];
    const float* prev = buf[(d & 1) ^ 1];
    if (u <= UU && t >= 0 && t < TT) {
      float a1 = (t >= 1) ? prev[u] + lbv : NEG;
      float a2 = (u >= 1) ? prev[u - 1] + lyv : NEG;
      float m = fmaxf(a1, a2);
      float val = (m <= -1e29f) ? NEG : m + __logf(1.f + __expf(-fabsf(a1 - a2)));
      cur[u] = val;
      if (t == tl - 1 && u == ul) {
        float lbt = lb[((size_t)b * TT + t) * UP1 + u];
        atomicAdd(out, -0.125f * (val + lbt));
      }
    }
    __syncthreads();
  }
}

// ---------------- launch ----------------
extern "C" void kernel_launch(void* const* d_in, const int* in_sizes, int n_in,
                              void* d_out, int out_size, void* d_ws, size_t ws_size,
                              hipStream_t stream) {
  (void)in_sizes; (void)n_in; (void)out_size;
  const float* xs    = (const float*)d_in[0];
  const int*   ys    = (const int*)d_in[1];
  const int*   xlen  = (const int*)d_in[2];
  const int*   ylen  = (const int*)d_in[3];
  const float* eWih0 = (const float*)d_in[4];
  const float* eWhh0 = (const float*)d_in[5];
  const float* ebih0 = (const float*)d_in[6];
  const float* ebhh0 = (const float*)d_in[7];
  const float* eWih1 = (const float*)d_in[8];
  const float* eWhh1 = (const float*)d_in[9];
  const float* ebih1 = (const float*)d_in[10];
  const float* ebhh1 = (const float*)d_in[11];
  const float* eWo   = (const float*)d_in[12];
  const float* ebo   = (const float*)d_in[13];
  const float* dWih  = (const float*)d_in[15];
  const float* dWhh  = (const float*)d_in[16];
  const float* dbih  = (const float*)d_in[17];
  const float* dbhh  = (const float*)d_in[18];
  const float* dWo   = (const float*)d_in[19];
  const float* dbo   = (const float*)d_in[20];

  char* ws = (char*)d_ws;
  const size_t OFF_XP0   = 1024;
  const size_t OFF_XPD   = OFF_XP0   + 20480000;  // 8*500*1280 f32
  const size_t OFF_H0    = OFF_XPD   + 4956160;   // 501 * 8*320 u32 (tagged, agent)
  const size_t OFF_H1    = OFF_H0    + 5130240;
  const size_t OFF_HD    = OFF_H1    + 5130240;   // 122 * 8*320 u32
  const size_t OFF_WB    = OFF_HD    + 1249280;
  const size_t OFF_WIH0B = OFF_WB    + 3276800;   // 4*1280*320 bf16
  const size_t OFF_XSB   = OFF_WIH0B + 245760;    // 1280*96 bf16
  const size_t OFF_WOB   = OFF_XSB   + 768000;    // 4000*96 bf16
  const size_t OFF_DWOB  = OFF_WOB   + 81920;
  const size_t OFF_B1P   = OFF_DWOB  + 81920;
  const size_t OFF_B0S   = OFF_B1P   + 5120;
  const size_t OFF_ENC2  = OFF_B0S   + 5120;
  const size_t OFF_DEC2  = OFF_ENC2  + 4096000;   // 500*16*128 f32
  const size_t OFF_LB    = OFF_DEC2  + 991232;    // 121*16*128 f32
  const size_t OFF_LY    = OFF_LB    + 1936000;   // 8*500*121 f32
  const size_t OFF_H0F   = OFF_LY    + 1920000;   // fast (same-XCD L2) h copies
  const size_t OFF_H1F   = OFF_H0F   + 5130240;
  const size_t OFF_HDF   = OFF_H1F   + 5130240;
  const size_t OFF_XCC   = OFF_HDF   + 1249280;   // 128 u32 XCD-id table
  const size_t OFF_XRES  = OFF_XCC   + 512;       // 128 u32 slot assignments
  const size_t TOTAL     = OFF_XRES  + 512;
  if (ws_size < TOTAL) return;

  float*    xp0   = (float*)(ws + OFF_XP0);
  float*    xpd   = (float*)(ws + OFF_XPD);
  unsigned* h0    = (unsigned*)(ws + OFF_H0);
  unsigned* h1    = (unsigned*)(ws + OFF_H1);
  unsigned* hd    = (unsigned*)(ws + OFF_HD);
  ushort*   wb    = (ushort*)(ws + OFF_WB);
  ushort*   wih0b = (ushort*)(ws + OFF_WIH0B);
  ushort*   xsb   = (ushort*)(ws + OFF_XSB);
  ushort*   wob   = (ushort*)(ws + OFF_WOB);
  ushort*   dwob  = (ushort*)(ws + OFF_DWOB);
  float*    b1p   = (float*)(ws + OFF_B1P);
  float*    b0s   = (float*)(ws + OFF_B0S);
  float*    enc2  = (float*)(ws + OFF_ENC2);
  float*    dec2  = (float*)(ws + OFF_DEC2);
  float*    lb    = (float*)(ws + OFF_LB);
  float*    ly    = (float*)(ws + OFF_LY);
  unsigned* h0f   = (unsigned*)(ws + OFF_H0F);
  unsigned* h1f   = (unsigned*)(ws + OFF_H1F);
  unsigned* hdf   = (unsigned*)(ws + OFF_HDF);
  unsigned* xtab  = (unsigned*)(ws + OFF_XCC);
  unsigned* xres  = (unsigned*)(ws + OFF_XRES);
  float*    out   = (float*)d_out;

  hipLaunchKernelGGL(prep_zero, dim3(10), dim3(256), 0, stream,
                     h0, h1, hd, h0f, h1f, hdf, out);
  hipLaunchKernelGGL(prep_w, dim3(8710), dim3(256), 0, stream,
                     eWhh0, eWih1, eWhh1, dWhh, eWih0, xs, eWo, dWo,
                     ebih1, ebhh1, ebih0, ebhh0,
                     wb, wih0b, xsb, wob, dwob, b1p, b0s);
  hipLaunchKernelGGL(xproj0_mfma, dim3(250), dim3(256), 0, stream, xsb, wih0b, b0s, xp0);
  hipLaunchKernelGGL(xprojd_g, dim3(968), dim3(256), 0, stream, ys, dWih, dbih, dbhh, xpd);
  hipLaunchKernelGGL(lstm_fused, dim3(128), dim3(512), 0, stream,
                     wb, b1p, xp0, xpd, h0, h1, hd, h0f, h1f, hdf, xtab, xres);
  hipLaunchKernelGGL(proj_mfma, dim3(500), dim3(256), 0, stream, h1, wob, ebo, enc2);
  hipLaunchKernelGGL(proj_mfma, dim3(121), dim3(256), 0, stream, hd, dwob, dbo, dec2);
  hipLaunchKernelGGL(lse_kernel, dim3(4000), dim3(256), 0, stream, enc2, dec2, ys, lb, ly);
  hipLaunchKernelGGL(dp_kernel, dim3(8), dim3(128), 0, stream, lb, ly, xlen, ylen, out);
}

// Round 3
// 2882.077 us; speedup vs baseline: 3.0516x; 1.4354x over previous
//
#include <hip/hip_runtime.h>

typedef __attribute__((ext_vector_type(8))) short s8v;   // 8 x bf16 (4 VGPRs)
typedef __attribute__((ext_vector_type(4))) float f4v;   // MFMA accumulator

#define BB 8
#define TT 500
#define UU 120
#define UP1 121
#define VV 128
#define HH 320
#define G4 1280

// ---------------- helpers ----------------
__device__ __forceinline__ unsigned short f2bf(float x) {
  unsigned u = __builtin_bit_cast(unsigned, x);
  unsigned r = (u + 0x7FFFu + ((u >> 16) & 1u)) >> 16;  // RNE
  return (unsigned short)r;
}
__device__ __forceinline__ float sigf(float x)   { return 1.f / (1.f + __expf(-x)); }
__device__ __forceinline__ float tanh_f(float x) { return 2.f / (1.f + __expf(-2.f * x)) - 1.f; }

// agent-scope (L3-coherent) relaxed atomics — proven transport
__device__ __forceinline__ unsigned ald32(const unsigned* p) {
  return __hip_atomic_load((unsigned*)p, __ATOMIC_RELAXED, __HIP_MEMORY_SCOPE_AGENT);
}
__device__ __forceinline__ void ast32(unsigned* p, unsigned v) {
  __hip_atomic_store(p, v, __ATOMIC_RELAXED, __HIP_MEMORY_SCOPE_AGENT);
}

// ---------------- prep: zero step-counters + out ----------------
__global__ void prep_zero(unsigned* cn0, unsigned* cn1, unsigned* cnd, float* out) {
  int i = threadIdx.x;
  cn0[i] = 0u; cn1[i] = 0u; cnd[i] = 0u;
  if (i == 0) out[0] = 0.f;
}

// ---------------- prep: bf16 conversions + bias folds ----------------
__global__ void prep_w(
    const float* __restrict__ whh0, const float* __restrict__ wih1,
    const float* __restrict__ whh1, const float* __restrict__ whhd,
    const float* __restrict__ wih0, const float* __restrict__ xs,
    const float* __restrict__ ewo,  const float* __restrict__ dwo,
    const float* __restrict__ bih1, const float* __restrict__ bhh1,
    const float* __restrict__ bih0, const float* __restrict__ bhh0,
    ushort* __restrict__ wb, ushort* __restrict__ wih0b, ushort* __restrict__ xsb,
    ushort* __restrict__ wob, ushort* __restrict__ dwob,
    float* __restrict__ bias1p, float* __restrict__ b0s)
{
  int i = blockIdx.x * blockDim.x + threadIdx.x;
  if (i < 1638400) {                       // 4 recurrent-ish mats [1280][320]
    int m = i / 409600, e = i - m * 409600;
    const float* src = (m == 0) ? whh0 : (m == 1) ? wih1 : (m == 2) ? whh1 : whhd;
    wb[i] = f2bf(src[e]);
  } else if (i < 1761280) {                // Wih0 [1280][80] -> [1280][96] zero-padded
    int e = i - 1638400;
    int row = e / 96, k = e - row * 96;
    wih0b[e] = (k < 80) ? f2bf(wih0[row * 80 + k]) : (ushort)0;
  } else if (i < 2145280) {                // xs [4000][80] -> [4000][96] zero-padded
    int e = i - 1761280;
    int row = e / 96, k = e - row * 96;
    xsb[e] = (k < 80) ? f2bf(xs[row * 80 + k]) : (ushort)0;
  } else if (i < 2186240) {                // enc_Wo [128][320]
    int e = i - 2145280;
    wob[e] = f2bf(ewo[e]);
  } else if (i < 2227200) {                // dec_Wo [128][320]
    int e = i - 2186240;
    dwob[e] = f2bf(dwo[e]);
  } else if (i < 2228480) {                // bias1 permuted [unit][gate]
    int e = i - 2227200;
    int uq = e >> 2, gq = e & 3;
    bias1p[e] = bih1[gq * HH + uq] + bhh1[gq * HH + uq];
  } else if (i < 2229760) {                // bih0+bhh0 summed (gate-row order)
    int e = i - 2228480;
    b0s[e] = bih0[e] + bhh0[e];
  }
}

// ---------------- xproj for layer0: [4000,96]bf16 @ [96,1280] -> xp0[b][t][u][g] f32 ----------------
__global__ __launch_bounds__(256) void xproj0_mfma(
    const ushort* __restrict__ xsb, const ushort* __restrict__ wih0b,
    const float* __restrict__ b0s, float* __restrict__ xp0)
{
  const int mt = blockIdx.x;                 // 250 tiles of 16 (b,t)-rows
  const int wave = threadIdx.x >> 6, lane = threadIdx.x & 63;
  const int q = lane >> 4, n16 = lane & 15;
  s8v a[3];
#pragma unroll
  for (int kt = 0; kt < 3; kt++)
    a[kt] = *(const s8v*)(xsb + (mt * 16 + n16) * 96 + kt * 32 + q * 8);
  for (int nt = wave; nt < 80; nt += 4) {
    s8v bf[3];
#pragma unroll
    for (int kt = 0; kt < 3; kt++)
      bf[kt] = *(const s8v*)(wih0b + (nt * 16 + n16) * 96 + kt * 32 + q * 8);
    f4v acc = {0.f, 0.f, 0.f, 0.f};
#pragma unroll
    for (int kt = 0; kt < 3; kt++)
      acc = __builtin_amdgcn_mfma_f32_16x16x32_bf16(a[kt], bf[kt], acc, 0, 0, 0);
    const int gr = nt * 16 + n16;            // D col = gate row
    const int gg = gr / HH;
    const int uu = gr - gg * HH;
    const float bias = b0s[gr];
#pragma unroll
    for (int r = 0; r < 4; r++) {
      int bt = mt * 16 + 4 * q + r;          // D row = (b,t) row
      xp0[(size_t)bt * G4 + uu * 4 + gg] = acc[r] + bias;
    }
  }
}

// ---------------- decoder input projection: one-hot gather ----------------
__global__ __launch_bounds__(256) void xprojd_g(
    const int* __restrict__ ys, const float* __restrict__ dWih,
    const float* __restrict__ dbih, const float* __restrict__ dbhh,
    float* __restrict__ xpd)
{
  const int blk = blockIdx.x;                // 968 = 8 * 121
  const int b = blk / UP1, u = blk - b * UP1;
  int colv = -1;
  if (u > 0) colv = ys[b * UU + (u - 1)] - 1;   // embed row id>=1 -> one-hot at id-1
  for (int i = threadIdx.x; i < G4; i += 256) {
    int uu = i >> 2, gg = i & 3;
    int row = gg * HH + uu;
    float v = dbih[row] + dbhh[row];
    if (colv >= 0) v += dWih[row * 127 + colv];
    xpd[((size_t)b * UP1 + u) * G4 + i] = v;
  }
}

// ---------------- fused recurrences, 3 stages x 5 wgs (512 thr = 8 waves) ----------------
// R0 compute structure. Transport v2: counter-gated handshake.
//   producer wave: 2 tagged h-stores -> s_waitcnt vmcnt(0) -> lane0 atomicAdd(cnt[t+1]).
//   consumer wave: spin on ONE broadcast dword (cnt[t]==40), then a single bulk
//   tagged read (tag-spin kept as bounded safety net). Kills the full-slice
//   re-poll storm that dominated R0 (and that R2 only relocated).
// C-init loads are issued at step top and added AFTER the MFMAs (latency hidden).
// t=0 skips transport entirely: LDS h-buffers are pre-zeroed.
__global__ __launch_bounds__(512, 1) void lstm_fused(
    const ushort* __restrict__ wb, const float* __restrict__ b1p,
    const float* __restrict__ xp0, const float* __restrict__ xpd,
    unsigned* __restrict__ h0u, unsigned* __restrict__ h1u, unsigned* __restrict__ hdu,
    unsigned* __restrict__ cn0, unsigned* __restrict__ cn1, unsigned* __restrict__ cnd)
{
  const int wg = blockIdx.x;
  const int stage = wg / 5;
  const int gw = wg - stage * 5;
  const int tid = threadIdx.x;
  const int wave = tid >> 6, lane = tid & 63;
  const int q = lane >> 4, n16 = lane & 15;
  const int uloc = n16 >> 2, g = n16 & 3;
  const int w = gw * 8 + wave;              // wave-in-stage [0,40)
  const int ubase = w * 8;                  // this wave owns units [ubase, ubase+8)
  const int bcol = n16 & 7;
  const bool act = (n16 < BB);
  const bool two = (stage == 1);

  __shared__ ushort hbS[2][16][328];        // double-buffered h (recurrent input)
  __shared__ ushort hbI[2][16][328];        // stage 1 only: h0[t+1] input

  // zero ALL rows once (t=0 state = zeros; rows 8..15 stay zero forever)
  for (int i = tid; i < 16 * 328; i += 512) {
    int r = i / 328, ci = i - r * 328;
    hbS[0][r][ci] = 0; hbS[1][r][ci] = 0;
    hbI[0][r][ci] = 0; hbI[1][r][ci] = 0;
  }

  const ushort* A = wb + (stage == 0 ? 0 : (stage == 1 ? 819200 : 1228800));
  s8v afr[2][10], ainfr[2][10];
#pragma unroll
  for (int tile = 0; tile < 2; tile++) {
    const int arow = g * HH + ubase + tile * 4 + uloc;
#pragma unroll
    for (int kt = 0; kt < 10; kt++)
      afr[tile][kt] = *(const s8v*)(A + arow * HH + kt * 32 + q * 8);
  }
  if (two) {
    const ushort* Win = wb + 409600;        // Wih1
#pragma unroll
    for (int tile = 0; tile < 2; tile++) {
      const int arow = g * HH + ubase + tile * 4 + uloc;
#pragma unroll
      for (int kt = 0; kt < 10; kt++)
        ainfr[tile][kt] = *(const s8v*)(Win + arow * HH + kt * 32 + q * 8);
    }
  }

  const int steps = (stage == 2) ? UP1 : TT;
  unsigned* hio = (stage == 0) ? h0u : ((stage == 1) ? h1u : hdu);
  unsigned* cS  = (stage == 0) ? cn0 : ((stage == 1) ? cn1 : cnd);

  f4v bias4[2];
  const float* xq = 0;
  if (stage == 0)      xq = xp0 + (size_t)bcol * TT * G4;
  else if (stage == 2) xq = xpd + (size_t)bcol * UP1 * G4;
  else {
#pragma unroll
    for (int tile = 0; tile < 2; tile++)
      bias4[tile] = *(const f4v*)(b1p + (ubase + tile * 4 + q) * 4);
  }

  float c0 = 0.f, c1 = 0.f;
  __syncthreads();                          // LDS zero-init visible

  for (int t = 0; t < steps; t++) {
    const int pb = t & 1;

    // ---- issue C-init loads early; consumed after the MFMA block ----
    f4v xq4[2];
    if (stage != 1) {
#pragma unroll
      for (int tile = 0; tile < 2; tile++)
        xq4[tile] = *(const f4v*)(xq + (size_t)t * G4 + (ubase + tile * 4 + q) * 4);
    }

    // ---- counter gate: one broadcast dword per needed producer set ----
    {
      int tries = 0;
      for (;;) {
        bool ok = (t == 0) || (ald32(cS + t) == 40u);
        if (two && ok) ok = (ald32(cn0 + t + 1) == 40u);
        if (ok || ++tries > (1 << 17)) break;
        __builtin_amdgcn_s_sleep(1);
      }
    }

    // ---- bulk tagged read of own batch-row, relay into LDS ----
    if (t > 0) {
      const unsigned* src = hio + (size_t)t * 2560 + wave * 320;
      unsigned v[5];
      int tries = 0;
      for (;;) {
#pragma unroll
        for (int j = 0; j < 5; j++) v[j] = ald32(src + j * 64 + lane);
        unsigned a = v[0] & v[1] & v[2] & v[3] & v[4];
        if (__all((int)(a & 1u)) || ++tries > (1 << 17)) break;
        __builtin_amdgcn_s_sleep(1);
      }
#pragma unroll
      for (int j = 0; j < 5; j++) hbS[pb][wave][j * 64 + lane] = (ushort)(v[j] >> 16);
    }
    if (two) {
      const unsigned* src = h0u + (size_t)(t + 1) * 2560 + wave * 320;
      unsigned v[5];
      int tries = 0;
      for (;;) {
#pragma unroll
        for (int j = 0; j < 5; j++) v[j] = ald32(src + j * 64 + lane);
        unsigned a = v[0] & v[1] & v[2] & v[3] & v[4];
        if (__all((int)(a & 1u)) || ++tries > (1 << 17)) break;
        __builtin_amdgcn_s_sleep(1);
      }
#pragma unroll
      for (int j = 0; j < 5; j++) hbI[pb][wave][j * 64 + lane] = (ushort)(v[j] >> 16);
    }
    __syncthreads();

    // ---- C-init (bias for stage1, zero otherwise; xq added after MFMAs) ----
    f4v acc[2];
    if (stage == 1) {
      acc[0] = bias4[0]; acc[1] = bias4[1];
    } else {
      acc[0] = (f4v){0.f, 0.f, 0.f, 0.f};
      acc[1] = (f4v){0.f, 0.f, 0.f, 0.f};
    }

    // ---- B-frags straight from LDS + MFMAs ----
#pragma unroll
    for (int kt = 0; kt < 10; kt++) {
      s8v b = *(const s8v*)&hbS[pb][n16][kt * 32 + q * 8];
      acc[0] = __builtin_amdgcn_mfma_f32_16x16x32_bf16(afr[0][kt], b, acc[0], 0, 0, 0);
      acc[1] = __builtin_amdgcn_mfma_f32_16x16x32_bf16(afr[1][kt], b, acc[1], 0, 0, 0);
    }
    if (two) {
#pragma unroll
      for (int kt = 0; kt < 10; kt++) {
        s8v b = *(const s8v*)&hbI[pb][n16][kt * 32 + q * 8];
        acc[0] = __builtin_amdgcn_mfma_f32_16x16x32_bf16(ainfr[0][kt], b, acc[0], 0, 0, 0);
        acc[1] = __builtin_amdgcn_mfma_f32_16x16x32_bf16(ainfr[1][kt], b, acc[1], 0, 0, 0);
      }
    }

    // ---- deferred C-init add (hidden under gate + MFMAs) ----
    if (stage != 1) {
#pragma unroll
      for (int tile = 0; tile < 2; tile++) {
        acc[tile][0] += xq4[tile][0]; acc[tile][1] += xq4[tile][1];
        acc[tile][2] += xq4[tile][2]; acc[tile][3] += xq4[tile][3];
      }
    }

    // ---- lane-local LSTM cell: acc[tile] = (i,f,g,o) for unit ubase+tile*4+q, batch n16 ----
    float hv0, hv1;
    {
      float ig = sigf(acc[0][0]), fg = sigf(acc[0][1]);
      float gv = tanh_f(acc[0][2]), og = sigf(acc[0][3]);
      c0 = fg * c0 + ig * gv; hv0 = og * tanh_f(c0);
    }
    {
      float ig = sigf(acc[1][0]), fg = sigf(acc[1][1]);
      float gv = tanh_f(acc[1][2]), og = sigf(acc[1][3]);
      c1 = fg * c1 + ig * gv; hv1 = og * tanh_f(c1);
    }
    if (act) {
      unsigned* dst = hio + (size_t)(t + 1) * 2560 + n16 * 320;
      ast32(dst + ubase + q,     (((unsigned)f2bf(hv0)) << 16) | 1u);
      ast32(dst + ubase + 4 + q, (((unsigned)f2bf(hv1)) << 16) | 1u);
    }
    // ---- publish: all wave stores at coherence point, then one counter add ----
    asm volatile("s_waitcnt vmcnt(0)" ::: "memory");
    if (lane == 0) atomicAdd(cS + t + 1, 1u);
  }
}

// ---------------- output projections: h(tagged u32)[16,320] @ Wo^T -> out2[t][16][128] ----------------
__global__ __launch_bounds__(256) void proj_mfma(
    const unsigned* __restrict__ hseq, const ushort* __restrict__ wo,
    const float* __restrict__ bo, float* __restrict__ out2)
{
  const int t = blockIdx.x;
  const int wave = threadIdx.x >> 6, lane = threadIdx.x & 63;
  const int q = lane >> 4, n16 = lane & 15;
  union F { unsigned u[4]; s8v v; };
  F a[10];
  const unsigned long long* hp =
      (const unsigned long long*)hseq + (size_t)(t + 1) * 1280 + n16 * 160 + q * 4;
#pragma unroll
  for (int kt = 0; kt < 10; kt++)
#pragma unroll
    for (int j = 0; j < 4; j++) {
      unsigned long long r = (n16 < BB) ? hp[kt * 16 + j] : 0ull;
      unsigned lo = (unsigned)r, hi = (unsigned)(r >> 32);
      a[kt].u[j] = (lo >> 16) | (hi & 0xFFFF0000u);
    }
  for (int j = 0; j < 2; j++) {
    int nt = wave * 2 + j;
    s8v bf[10];
#pragma unroll
    for (int kt = 0; kt < 10; kt++)
      bf[kt] = *(const s8v*)(wo + (nt * 16 + n16) * HH + kt * 32 + q * 8);
    f4v acc = {0.f, 0.f, 0.f, 0.f};
#pragma unroll
    for (int kt = 0; kt < 10; kt++)
      acc = __builtin_amdgcn_mfma_f32_16x16x32_bf16(a[kt].v, bf[kt], acc, 0, 0, 0);
    int v = nt * 16 + n16;
    float bias = bo[v];
    if (q < 2) {
#pragma unroll
      for (int r = 0; r < 4; r++) {
        int b = 4 * q + r;                   // D row = batch
        out2[((size_t)t * 16 + b) * VV + v] = acc[r] + bias;
      }
    }
  }
}

// ---------------- per-cell logsumexp over V: produce lb[b][t][u], ly[b][t][u] ----------------
__global__ __launch_bounds__(256) void lse_kernel(
    const float* __restrict__ enc2, const float* __restrict__ dec2,
    const int* __restrict__ ys, float* __restrict__ lb, float* __restrict__ ly)
{
  const int blk = blockIdx.x;                // 4000 = 8*500
  const int b = blk / TT, t = blk - b * TT;
  const int wave = threadIdx.x >> 6, lane = threadIdx.x & 63;
  const float* er = enc2 + ((size_t)t * 16 + b) * VV;
  const float e0 = er[lane], e1 = er[lane + 64];
  for (int u = wave; u < UP1; u += 4) {
    const float* dr = dec2 + ((size_t)u * 16 + b) * VV;
    float s0 = e0 + dr[lane], s1 = e1 + dr[lane + 64];
    float mx = fmaxf(s0, s1);
#pragma unroll
    for (int off = 32; off >= 1; off >>= 1) mx = fmaxf(mx, __shfl_xor(mx, off));
    float p = __expf(s0 - mx) + __expf(s1 - mx);
#pragma unroll
    for (int off = 32; off >= 1; off >>= 1) p += __shfl_xor(p, off);
    float lsev = mx + __logf(p);
    if (u < UU) {
      int y = ys[b * UU + u];                // in [1,127]
      float sy = (y < 64) ? __shfl(s0, y) : __shfl(s1, y - 64);
      if (lane == 0) ly[((size_t)b * TT + t) * UU + u] = sy - lsev;
    }
    if (lane == 0) lb[((size_t)b * TT + t) * UP1 + u] = s0 - lsev;  // lane0: v=0
  }
}

// ---------------- anti-diagonal forward DP, one block per sample ----------------
__global__ __launch_bounds__(128) void dp_kernel(
    const float* __restrict__ lb, const float* __restrict__ ly,
    const int* __restrict__ xlen, const int* __restrict__ ylen,
    float* __restrict__ out)
{
  const int b = blockIdx.x;
  const int u = threadIdx.x;
  __shared__ float buf[2][UP1];
  const int tl = xlen[b], ul = ylen[b];
  if (u == 0) buf[0][0] = 0.f;
  __syncthreads();
  const float NEG = -1e30f;
  float nlb = 0.f, nly = 0.f;
  {
    int tn = 1 - u;
    if (u <= UU && tn >= 1 && tn < TT) nlb = lb[((size_t)b * TT + tn - 1) * UP1 + u];
    if (u >= 1 && u <= UU && tn >= 0 && tn < TT) nly = ly[((size_t)b * TT + tn) * UU + (u - 1)];
  }
  for (int d = 1; d <= TT - 1 + UU; d++) {   // up to 619
    float lbv = nlb, lyv = nly;
    {
      int tn = (d + 1) - u;
      nlb = 0.f; nly = 0.f;
      if (u <= UU && tn >= 1 && tn < TT) nlb = lb[((size_t)b * TT + tn - 1) * UP1 + u];
      if (u >= 1 && u <= UU && tn >= 0 && tn < TT) nly = ly[((size_t)b * TT + tn) * UU + (u - 1)];
    }
    const int t = d - u;
    float* cur = buf[d & 1];
    const float* prev = buf[(d & 1) ^ 1];
    if (u <= UU && t >= 0 && t < TT) {
      float a1 = (t >= 1) ? prev[u] + lbv : NEG;
      float a2 = (u >= 1) ? prev[u - 1] + lyv : NEG;
      float m = fmaxf(a1, a2);
      float val = (m <= -1e29f) ? NEG : m + __logf(1.f + __expf(-fabsf(a1 - a2)));
      cur[u] = val;
      if (t == tl - 1 && u == ul) {
        float lbt = lb[((size_t)b * TT + t) * UP1 + u];
        atomicAdd(out, -0.125f * (val + lbt));
      }
    }
    __syncthreads();
  }
}

// ---------------- launch ----------------
extern "C" void kernel_launch(void* const* d_in, const int* in_sizes, int n_in,
                              void* d_out, int out_size, void* d_ws, size_t ws_size,
                              hipStream_t stream) {
  (void)in_sizes; (void)n_in; (void)out_size;
  const float* xs    = (const float*)d_in[0];
  const int*   ys    = (const int*)d_in[1];
  const int*   xlen  = (const int*)d_in[2];
  const int*   ylen  = (const int*)d_in[3];
  const float* eWih0 = (const float*)d_in[4];
  const float* eWhh0 = (const float*)d_in[5];
  const float* ebih0 = (const float*)d_in[6];
  const float* ebhh0 = (const float*)d_in[7];
  const float* eWih1 = (const float*)d_in[8];
  const float* eWhh1 = (const float*)d_in[9];
  const float* ebih1 = (const float*)d_in[10];
  const float* ebhh1 = (const float*)d_in[11];
  const float* eWo   = (const float*)d_in[12];
  const float* ebo   = (const float*)d_in[13];
  const float* dWih  = (const float*)d_in[15];
  const float* dWhh  = (const float*)d_in[16];
  const float* dbih  = (const float*)d_in[17];
  const float* dbhh  = (const float*)d_in[18];
  const float* dWo   = (const float*)d_in[19];
  const float* dbo   = (const float*)d_in[20];

  char* ws = (char*)d_ws;
  const size_t OFF_XP0   = 1024;
  const size_t OFF_XPD   = OFF_XP0   + 20480000;  // 8*500*1280 f32
  const size_t OFF_H0    = OFF_XPD   + 4956160;   // 501 * 8*320 u32 (tagged, agent)
  const size_t OFF_H1    = OFF_H0    + 5130240;
  const size_t OFF_HD    = OFF_H1    + 5130240;   // 122 * 8*320 u32
  const size_t OFF_WB    = OFF_HD    + 1249280;
  const size_t OFF_WIH0B = OFF_WB    + 3276800;   // 4*1280*320 bf16
  const size_t OFF_XSB   = OFF_WIH0B + 245760;    // 1280*96 bf16
  const size_t OFF_WOB   = OFF_XSB   + 768000;    // 4000*96 bf16
  const size_t OFF_DWOB  = OFF_WOB   + 81920;
  const size_t OFF_B1P   = OFF_DWOB  + 81920;
  const size_t OFF_B0S   = OFF_B1P   + 5120;
  const size_t OFF_ENC2  = OFF_B0S   + 5120;
  const size_t OFF_DEC2  = OFF_ENC2  + 4096000;   // 500*16*128 f32
  const size_t OFF_LB    = OFF_DEC2  + 991232;    // 121*16*128 f32
  const size_t OFF_LY    = OFF_LB    + 1936000;   // 8*500*121 f32
  const size_t OFF_CN0   = OFF_LY    + 1920000;   // 512 u32 step counters per stage
  const size_t OFF_CN1   = OFF_CN0   + 2048;
  const size_t OFF_CND   = OFF_CN1   + 2048;
  const size_t TOTAL     = OFF_CND   + 2048;
  if (ws_size < TOTAL) return;

  float*    xp0   = (float*)(ws + OFF_XP0);
  float*    xpd   = (float*)(ws + OFF_XPD);
  unsigned* h0    = (unsigned*)(ws + OFF_H0);
  unsigned* h1    = (unsigned*)(ws + OFF_H1);
  unsigned* hd    = (unsigned*)(ws + OFF_HD);
  ushort*   wb    = (ushort*)(ws + OFF_WB);
  ushort*   wih0b = (ushort*)(ws + OFF_WIH0B);
  ushort*   xsb   = (ushort*)(ws + OFF_XSB);
  ushort*   wob   = (ushort*)(ws + OFF_WOB);
  ushort*   dwob  = (ushort*)(ws + OFF_DWOB);
  float*    b1p   = (float*)(ws + OFF_B1P);
  float*    b0s   = (float*)(ws + OFF_B0S);
  float*    enc2  = (float*)(ws + OFF_ENC2);
  float*    dec2  = (float*)(ws + OFF_DEC2);
  float*    lb    = (float*)(ws + OFF_LB);
  float*    ly    = (float*)(ws + OFF_LY);
  unsigned* cn0   = (unsigned*)(ws + OFF_CN0);
  unsigned* cn1   = (unsigned*)(ws + OFF_CN1);
  unsigned* cnd   = (unsigned*)(ws + OFF_CND);
  float*    out   = (float*)d_out;

  hipLaunchKernelGGL(prep_zero, dim3(1), dim3(512), 0, stream, cn0, cn1, cnd, out);
  hipLaunchKernelGGL(prep_w, dim3(8710), dim3(256), 0, stream,
                     eWhh0, eWih1, eWhh1, dWhh, eWih0, xs, eWo, dWo,
                     ebih1, ebhh1, ebih0, ebhh0,
                     wb, wih0b, xsb, wob, dwob, b1p, b0s);
  hipLaunchKernelGGL(xproj0_mfma, dim3(250), dim3(256), 0, stream, xsb, wih0b, b0s, xp0);
  hipLaunchKernelGGL(xprojd_g, dim3(968), dim3(256), 0, stream, ys, dWih, dbih, dbhh, xpd);
  hipLaunchKernelGGL(lstm_fused, dim3(15), dim3(512), 0, stream,
                     wb, b1p, xp0, xpd, h0, h1, hd, cn0, cn1, cnd);
  hipLaunchKernelGGL(proj_mfma, dim3(500), dim3(256), 0, stream, h1, wob, ebo, enc2);
  hipLaunchKernelGGL(proj_mfma, dim3(121), dim3(256), 0, stream, hd, dwob, dbo, dec2);
  hipLaunchKernelGGL(lse_kernel, dim3(4000), dim3(256), 0, stream, enc2, dec2, ys, lb, ly);
  hipLaunchKernelGGL(dp_kernel, dim3(8), dim3(128), 0, stream, lb, ly, xlen, ylen, out);
}